// Round 3
// baseline (28144.498 us; speedup 1.0000x reference)
//
#include <hip/hip_runtime.h>
#include <hip/hip_bf16.h>
#include <stdint.h>

using bf16 = __hip_bfloat16;
typedef short bf16x8 __attribute__((ext_vector_type(8)));
typedef float f32x4 __attribute__((ext_vector_type(4)));

#define BB 64
#define LL 12
#define DD 768
#define HH 12
#define HDD 64
#define FFD 3072
#define NN 197
#define NPP 196
#define NCC 100
#define MROWS (BB * NN)      // 12608
#define MPAD  12672          // 99*128

__device__ __forceinline__ float bflo(uint32_t u) { return __uint_as_float(u << 16); }
__device__ __forceinline__ float bfhi(uint32_t u) { return __uint_as_float(u & 0xffff0000u); }
__device__ __forceinline__ uint32_t f2bf_bits(float f) {
    bf16 h = __float2bfloat16(f);           // RNE
    union { uint16_t u; bf16 b; } c; c.b = h;
    return (uint32_t)c.u;
}
__device__ __forceinline__ uint32_t pk2(float a, float b) { return f2bf_bits(a) | (f2bf_bits(b) << 16); }
__device__ __forceinline__ uint4 pack8(float4 a, float4 b) {
    uint4 r; r.x = pk2(a.x, a.y); r.y = pk2(a.z, a.w); r.z = pk2(b.x, b.y); r.w = pk2(b.z, b.w); return r;
}

// ---------------- patchify: inputs fp32 [B,3,224,224] -> P bf16 [B*196, 768] (timm order) ----------------
__global__ __launch_bounds__(256) void patchify_kernel(const float* __restrict__ inp, bf16* __restrict__ P) {
    int i = blockIdx.x * 256 + threadIdx.x;             // 8 elements per thread
    const int total = NPP * BB * 96;
    if (i >= total) return;
    int c8 = i % 96;
    int r  = i / 96;
    int b = r / NPP, p = r % NPP;
    int ph = p / 14, pw = p % 14;
    int c = c8 * 8;
    int ch = c >> 8;
    int rem = c & 255;
    int ii = rem >> 4, jj = rem & 15;
    const float* src = inp + ((size_t)((b * 3 + ch) * 224 + ph * 16 + ii)) * 224 + pw * 16 + jj;
    float4 f0 = *(const float4*)src;
    float4 f1 = *(const float4*)(src + 4);
    *(uint4*)(P + (size_t)r * DD + c) = pack8(f0, f1);
}

// ---------------- GEMM: C[M,N] = A_bf16[M,K] @ W_f32[N,K]^T + bias (+res)(+gelu) ----------------
template<bool RES, bool GELU, bool OUTF32>
__global__ __launch_bounds__(256) void gemm_bt(
    const bf16* __restrict__ A, const float* __restrict__ W, const float* __restrict__ bias,
    const float* res, float* outf, bf16* outb, int M, int N, int K)
{
    __shared__ __align__(16) bf16 As[128 * 64];
    __shared__ __align__(16) bf16 Bs[128 * 64];
    const int t = threadIdx.x;
    const int lane = t & 63;
    const int wv = t >> 6;
    const int q15 = lane & 15, quad = lane >> 4;
    const int row0 = blockIdx.x * 128, col0 = blockIdx.y * 128;
    const int wm = (wv >> 1) * 64, wn = (wv & 1) * 64;

    f32x4 acc[4][4];
#pragma unroll
    for (int a = 0; a < 4; a++)
#pragma unroll
        for (int b2 = 0; b2 < 4; b2++) { f32x4 z = {0.f, 0.f, 0.f, 0.f}; acc[a][b2] = z; }

    const bf16*  Ag = A + (size_t)(row0 + (t >> 3)) * K + (t & 7) * 8;
    const float* Wg = W + (size_t)(col0 + (t >> 3)) * K + (t & 7) * 8;
    bf16* lA = As + t * 8;   // row t>>3, col (t&7)*8
    bf16* lB = Bs + t * 8;

    for (int kt = 0; kt < K; kt += 64) {
        uint4 av[4], wv4[4];
#pragma unroll
        for (int qi = 0; qi < 4; qi++) {
            av[qi] = *(const uint4*)(Ag + (size_t)qi * 32 * K + kt);
            const float* wp = Wg + (size_t)qi * 32 * K + kt;
            wv4[qi] = pack8(*(const float4*)wp, *(const float4*)(wp + 4));
        }
        __syncthreads();   // previous iteration's LDS reads complete
#pragma unroll
        for (int qi = 0; qi < 4; qi++) {
            *(uint4*)(lA + qi * 2048) = av[qi];
            *(uint4*)(lB + qi * 2048) = wv4[qi];
        }
        __syncthreads();
#pragma unroll
        for (int k0 = 0; k0 < 64; k0 += 32) {
            bf16x8 af[4], bfv[4];
#pragma unroll
            for (int mi = 0; mi < 4; mi++)
                af[mi] = *(const bf16x8*)(As + (wm + mi * 16 + q15) * 64 + k0 + quad * 8);
#pragma unroll
            for (int ni = 0; ni < 4; ni++)
                bfv[ni] = *(const bf16x8*)(Bs + (wn + ni * 16 + q15) * 64 + k0 + quad * 8);
#pragma unroll
            for (int mi = 0; mi < 4; mi++)
#pragma unroll
                for (int ni = 0; ni < 4; ni++)
                    acc[mi][ni] = __builtin_amdgcn_mfma_f32_16x16x32_bf16(af[mi], bfv[ni], acc[mi][ni], 0, 0, 0);
        }
    }

#pragma unroll
    for (int mi = 0; mi < 4; mi++) {
#pragma unroll
        for (int ni = 0; ni < 4; ni++) {
            const int c = col0 + wn + ni * 16 + q15;
            const float bv = bias[c];
#pragma unroll
            for (int r = 0; r < 4; r++) {
                const int row = row0 + wm + mi * 16 + quad * 4 + r;
                if (row < M) {
                    float v = acc[mi][ni][r] + bv;
                    if (RES) v += res[(size_t)row * N + c];
                    if (GELU) v = 0.5f * v * (1.0f + erff(v * 0.70710678118654752f));
                    if (OUTF32) outf[(size_t)row * N + c] = v;
                    else outb[(size_t)row * N + c] = __float2bfloat16(v);
                }
            }
        }
    }
}

// ---------------- assemble xb = concat(cls, patches) + pos (fp32 residual) ----------------
__global__ __launch_bounds__(256) void assemble_x0_kernel(const float* __restrict__ tmp,
    const float* __restrict__ cls, const float* __restrict__ pos, float* __restrict__ xb)
{
    size_t i = (size_t)blockIdx.x * 256 + threadIdx.x;
    if (i >= (size_t)MROWS * DD) return;
    int c = (int)(i % DD);
    int r = (int)(i / DD);
    int b = r / NN, tt = r % NN;
    float v;
    if (tt == 0) v = cls[c];
    else        v = tmp[(size_t)(b * NPP + tt - 1) * DD + c];
    v += pos[(size_t)tt * DD + c];
    xb[i] = v;
}

// ---------------- LayerNorm row kernel: fp32 in -> bf16 out, fp32 params ----------------
__global__ __launch_bounds__(256) void ln_kernel(const float* __restrict__ x, long long rstride,
    const float* __restrict__ sc, const float* __restrict__ bi, bf16* __restrict__ out)
{
    int r = blockIdx.x;
    const float* xr = x + (size_t)r * rstride;
    int t = threadIdx.x;
    float v0 = xr[t], v1 = xr[t + 256], v2 = xr[t + 512];
    __shared__ float r1[256], r2[256];
    r1[t] = v0 + v1 + v2;
    r2[t] = v0 * v0 + v1 * v1 + v2 * v2;
    __syncthreads();
    for (int o = 128; o > 0; o >>= 1) {
        if (t < o) { r1[t] += r1[t + o]; r2[t] += r2[t + o]; }
        __syncthreads();
    }
    float mu = r1[0] * (1.f / 768.f);
    float var = fmaxf(r2[0] * (1.f / 768.f) - mu * mu, 0.f);
    float rs = rsqrtf(var + 1e-6f);
    bf16* o_ = out + (size_t)r * DD;
    o_[t]       = __float2bfloat16((v0 - mu) * rs * sc[t]       + bi[t]);
    o_[t + 256] = __float2bfloat16((v1 - mu) * rs * sc[t + 256] + bi[t + 256]);
    o_[t + 512] = __float2bfloat16((v2 - mu) * rs * sc[t + 512] + bi[t + 512]);
}

// ---------------- attention: one block per (b, head); lane = q-row; online softmax ----------------
__global__ __launch_bounds__(256) void attn_kernel(const bf16* __restrict__ qkv,
    const bf16* __restrict__ pk, const bf16* __restrict__ pv,
    int n_extra, int pstride, bf16* __restrict__ out)
{
    const int bh = blockIdx.x;
    const int b = bh / HH, hh = bh % HH;
    const int Nk = NN + n_extra;
    __shared__ __align__(16) bf16 kl[217 * 64];
    __shared__ __align__(16) bf16 vl[217 * 64];
    const int t = threadIdx.x;
    for (int idx = t; idx < Nk * 8; idx += 256) {
        int j = idx >> 3, c = (idx & 7) * 8;
        const bf16 *ks, *vs;
        if (j < NN) {
            const bf16* base = qkv + ((size_t)(b * NN + j)) * 2304 + hh * 64 + c;
            ks = base + 768; vs = base + 1536;
        } else {
            size_t off = (size_t)(pstride ? b * pstride : 0) + (size_t)(j - NN) * DD + hh * 64 + c;
            ks = pk + off; vs = pv + off;
        }
        *(uint4*)(kl + j * 64 + c) = *(const uint4*)ks;
        *(uint4*)(vl + j * 64 + c) = *(const uint4*)vs;
    }
    __syncthreads();

    int row = (t < NN) ? t : (NN - 1);
    float qv[64];
    {
        const uint32_t* qs = (const uint32_t*)(qkv + ((size_t)(b * NN + row)) * 2304 + hh * 64);
#pragma unroll
        for (int d2 = 0; d2 < 32; d2++) {
            uint32_t u = qs[d2];
            qv[d2 * 2] = bflo(u); qv[d2 * 2 + 1] = bfhi(u);
        }
    }
    float acc[64];
#pragma unroll
    for (int d = 0; d < 64; d++) acc[d] = 0.f;
    float mx = -1e30f, l = 0.f;

    for (int j = 0; j < Nk; j++) {
        const uint32_t* kr = (const uint32_t*)(kl + j * 64);
        float s = 0.f;
#pragma unroll
        for (int d2 = 0; d2 < 32; d2++) {
            uint32_t u = kr[d2];
            s += qv[d2 * 2] * bflo(u) + qv[d2 * 2 + 1] * bfhi(u);
        }
        s *= 0.125f;
        if (s > mx) {
            float corr = __expf(mx - s);
            l *= corr;
#pragma unroll
            for (int d = 0; d < 64; d++) acc[d] *= corr;
            mx = s;
        }
        float p = __expf(s - mx);
        l += p;
        const uint32_t* vr = (const uint32_t*)(vl + j * 64);
#pragma unroll
        for (int d2 = 0; d2 < 32; d2++) {
            uint32_t u = vr[d2];
            acc[d2 * 2]     += p * bflo(u);
            acc[d2 * 2 + 1] += p * bfhi(u);
        }
    }

    if (t < NN) {
        float inv = 1.f / l;
        uint32_t* dst = (uint32_t*)(out + ((size_t)(b * NN + row)) * DD + hh * 64);
#pragma unroll
        for (int d2 = 0; d2 < 32; d2++) {
            uint32_t lo = f2bf_bits(acc[d2 * 2] * inv);
            uint32_t hi = f2bf_bits(acc[d2 * 2 + 1] * inv);
            dst[d2] = lo | (hi << 16);
        }
    }
}

// ---------------- key selection + mask (fp32 key_emb / mask_param) ----------------
__global__ __launch_bounds__(256) void select_kernel(const float* __restrict__ xq, const float* __restrict__ ke,
    const float* __restrict__ mp, int* __restrict__ idxo, float* __restrict__ masko)
{
    __shared__ float kn[10];
    __shared__ int sidx[64];
    int t = threadIdx.x;
    if (t < 10) {
        float s = 0.f;
        for (int d = 0; d < DD; d++) { float v = ke[t * DD + d]; s += v * v; }
        kn[t] = sqrtf(s) + 1e-8f;
    }
    __syncthreads();
    if (t < BB) {
        const float* q = xq + (size_t)t * NN * DD;   // row (b, 0)
        float qs = 0.f;
        for (int d = 0; d < DD; d++) qs += q[d] * q[d];
        float qn = sqrtf(qs) + 1e-8f;
        float best = -1e30f; int bi = 0;
        for (int k = 0; k < 10; k++) {
            float dot = 0.f;
            for (int d = 0; d < DD; d++) dot += q[d] * ke[k * DD + d];
            float sim = dot / (qn * kn[k]);          // argmin(1-sim) == argmax(sim), first-max tie rule
            if (sim > best) { best = sim; bi = k; }
        }
        sidx[t] = bi; idxo[t] = bi;
    }
    __syncthreads();
    for (int i = t; i < BB * NCC; i += 256) {
        int b = i / NCC, c = i % NCC;
        float v = mp[sidx[b] * NCC + c];
        masko[i] = 2.f / (1.f + __expf(-v));
    }
}

// e_sel layout: [layer(3)][part(2)][B][20][768], fp32 -> bf16
__global__ __launch_bounds__(256) void gather_e_kernel(const float* __restrict__ ep, const int* __restrict__ idx,
                                                       bf16* __restrict__ es)
{
    int i = blockIdx.x * 256 + threadIdx.x;
    const int total = BB * 120 * 96;
    if (i >= total) return;
    int c = (i % 96) * 8;
    int rr = i / 96;
    int trow = rr % 120, b = rr / 120;
    int li = trow / 40, part = (trow / 20) % 2, tk = trow % 20;
    const float* s = ep + ((size_t)(idx[b] * 120 + trow)) * DD + c;
    *(uint4*)(es + ((size_t)(((li * 2 + part) * BB + b) * 20 + tk)) * DD + c)
        = pack8(*(const float4*)s, *(const float4*)(s + 4));
}

// gstage layout: [layer(2)][part(2)][128 rows (5 valid)][768], fp32 -> bf16
__global__ __launch_bounds__(64) void gstage_kernel(const float* __restrict__ gp, bf16* __restrict__ gs) {
    int i = blockIdx.x * 64 + threadIdx.x;
    if (i >= 20 * 96) return;
    int c = (i % 96) * 8;
    int row = i / 96;
    int li = row / 10, part = (row / 5) % 2, tk = row % 5;
    const float* s = gp + (size_t)row * DD + c;
    *(uint4*)(gs + ((size_t)((li * 2 + part) * 128 + tk)) * DD + c)
        = pack8(*(const float4*)s, *(const float4*)(s + 4));
}

// ---------------- head: logits = feat @ head_w^T + head_b, * mask (fp32 out) ----------------
__global__ __launch_bounds__(256) void head_kernel(const bf16* __restrict__ feat, const float* __restrict__ hw,
    const float* __restrict__ hb, const float* __restrict__ mask, float* __restrict__ out)
{
    int i = blockIdx.x * 256 + threadIdx.x;
    if (i >= BB * NCC) return;
    int b = i / NCC, c = i % NCC;
    const bf16*  f = feat + (size_t)b * DD;
    const float* w = hw + (size_t)c * DD;
    float s = 0.f;
    for (int d = 0; d < DD; d++) s += __bfloat162float(f[d]) * w[d];
    s += hb[c];
    out[i] = s * mask[i];
}

extern "C" void kernel_launch(void* const* d_in, const int* in_sizes, int n_in,
                              void* d_out, int out_size, void* d_ws, size_t ws_size,
                              hipStream_t stream)
{
    const float* inp       = (const float*)d_in[0];
    const float* patch_w   = (const float*)d_in[1];
    const float* patch_b   = (const float*)d_in[2];
    const float* cls_tok   = (const float*)d_in[3];
    const float* pos_emb   = (const float*)d_in[4];
    const float* ln1_s     = (const float*)d_in[5];
    const float* ln1_b     = (const float*)d_in[6];
    const float* qkv_w     = (const float*)d_in[7];
    const float* qkv_b     = (const float*)d_in[8];
    const float* proj_w    = (const float*)d_in[9];
    const float* proj_b    = (const float*)d_in[10];
    const float* ln2_s     = (const float*)d_in[11];
    const float* ln2_b     = (const float*)d_in[12];
    const float* fc1_w     = (const float*)d_in[13];
    const float* fc1_b     = (const float*)d_in[14];
    const float* fc2_w     = (const float*)d_in[15];
    const float* fc2_b     = (const float*)d_in[16];
    const float* norm_s    = (const float*)d_in[17];
    const float* norm_b    = (const float*)d_in[18];
    const float* head_w    = (const float*)d_in[19];
    const float* head_b    = (const float*)d_in[20];
    const float* key_emb   = (const float*)d_in[21];
    const float* mask_p    = (const float*)d_in[22];
    const float* g_prompts = (const float*)d_in[23];
    const float* e_prompts = (const float*)d_in[24];

    char* p = (char*)d_ws;
    auto alloc = [&](size_t bytes) { char* r = p; p += (bytes + 255) & ~(size_t)255; return r; };

    // ---- lifetime-aliased workspace (~153 MB total) ----
    float* xb  = (float*)alloc((size_t)MROWS * DD * 4);       // 38.7 MB, persistent residual
    bf16*  h   = (bf16*) alloc((size_t)MPAD * DD * 2);        // 19.5 MB, ln-out / attn-out (aliased)
    char*  QF  = (char*) alloc((size_t)MPAD * FFD * 2);       // 77.9 MB union: P+tmp | qkvb | ffb
    bf16*  e_sel = (bf16*) alloc((size_t)6 * 1280 * DD * 2);  // 11.8 MB
    bf16*  gst   = (bf16*) alloc((size_t)4 * 128 * DD * 2);
    bf16*  pkg   = (bf16*) alloc((size_t)128 * DD * 2);
    bf16*  pvg   = (bf16*) alloc((size_t)128 * DD * 2);
    bf16*  pke   = (bf16*) alloc((size_t)1280 * DD * 2);
    bf16*  pve   = (bf16*) alloc((size_t)1280 * DD * 2);
    bf16*  feat  = (bf16*) alloc((size_t)BB * DD * 2);
    float* maskf = (float*)alloc((size_t)BB * NCC * 4);
    int*   idxp  = (int*)  alloc((size_t)BB * 4);

    bf16*  qkvb = (bf16*)QF;                       // live: qkv-gemm -> attn
    bf16*  ffb  = (bf16*)QF;                       // live: fc1 -> fc2 (qkvb dead by then)
    bf16*  ato  = h;                               // attn-out aliases h (h dead after qkv gemm)

    auto embed = [&]() {
        bf16*  P   = (bf16*)QF;                    // 19.3 MB at offset 0
        float* tmp = (float*)(QF + (size_t)20 * 1024 * 1024);  // 38.5 MB at +20 MB (disjoint)
        patchify_kernel<<<(NPP * BB * 96) / 256, 256, 0, stream>>>(inp, P);
        gemm_bt<false, false, true><<<dim3(98, 6), 256, 0, stream>>>(P, patch_w, patch_b, nullptr, tmp, nullptr,
                                                                     NPP * BB, DD, DD);
        assemble_x0_kernel<<<(MROWS * DD) / 256, 256, 0, stream>>>(tmp, cls_tok, pos_emb, xb);
    };

    auto layer = [&](int n, int n_extra, const bf16* pkp, const bf16* pvp, int pstride) {
        ln_kernel<<<MROWS, 256, 0, stream>>>(xb, (long long)DD, ln1_s + n * DD, ln1_b + n * DD, h);
        gemm_bt<false, false, false><<<dim3(99, 18), 256, 0, stream>>>(
            h, qkv_w + (size_t)n * 2304 * DD, qkv_b + n * 2304, nullptr, nullptr, qkvb, MROWS, 2304, DD);
        if (n_extra == 5) {
            const bf16* gk = gst + (size_t)(n * 2 + 0) * 128 * DD;
            const bf16* gv = gst + (size_t)(n * 2 + 1) * 128 * DD;
            gemm_bt<false, false, false><<<dim3(1, 6), 256, 0, stream>>>(
                gk, qkv_w + ((size_t)n * 2304 + 768) * DD, qkv_b + n * 2304 + 768, nullptr, nullptr, pkg, 5, DD, DD);
            gemm_bt<false, false, false><<<dim3(1, 6), 256, 0, stream>>>(
                gv, qkv_w + ((size_t)n * 2304 + 1536) * DD, qkv_b + n * 2304 + 1536, nullptr, nullptr, pvg, 5, DD, DD);
        } else if (n_extra == 20) {
            int li = n - 2;
            const bf16* ek = e_sel + (size_t)(li * 2 + 0) * 1280 * DD;
            const bf16* ev = e_sel + (size_t)(li * 2 + 1) * 1280 * DD;
            gemm_bt<false, false, false><<<dim3(10, 6), 256, 0, stream>>>(
                ek, qkv_w + ((size_t)n * 2304 + 768) * DD, qkv_b + n * 2304 + 768, nullptr, nullptr, pke, 1280, DD, DD);
            gemm_bt<false, false, false><<<dim3(10, 6), 256, 0, stream>>>(
                ev, qkv_w + ((size_t)n * 2304 + 1536) * DD, qkv_b + n * 2304 + 1536, nullptr, nullptr, pve, 1280, DD, DD);
        }
        attn_kernel<<<BB * HH, 256, 0, stream>>>(qkvb, pkp, pvp, n_extra, pstride, ato);
        gemm_bt<true, false, true><<<dim3(99, 6), 256, 0, stream>>>(
            ato, proj_w + (size_t)n * DD * DD, proj_b + n * DD, xb, xb, nullptr, MROWS, DD, DD);
        ln_kernel<<<MROWS, 256, 0, stream>>>(xb, (long long)DD, ln2_s + n * DD, ln2_b + n * DD, h);
        gemm_bt<false, true, false><<<dim3(99, 24), 256, 0, stream>>>(
            h, fc1_w + (size_t)n * FFD * DD, fc1_b + n * FFD, nullptr, nullptr, ffb, MROWS, FFD, DD);
        gemm_bt<true, false, true><<<dim3(99, 6), 256, 0, stream>>>(
            ffb, fc2_w + (size_t)n * DD * FFD, fc2_b + n * DD, xb, xb, nullptr, MROWS, DD, FFD);
    };

    // 1+2) embed, then frozen query pass
    embed();
    for (int n = 0; n < LL; n++) layer(n, 0, nullptr, nullptr, 0);

    // 3) key selection, mask, prompt gathers (uses pass-1 xb; must precede re-embed)
    select_kernel<<<1, 256, 0, stream>>>(xb, key_emb, mask_p, idxp, maskf);
    gather_e_kernel<<<(BB * 120 * 96) / 256, 256, 0, stream>>>(e_prompts, idxp, e_sel);
    gstage_kernel<<<30, 64, 0, stream>>>(g_prompts, gst);

    // 4) re-embed, then prompted pass
    embed();
    for (int n = 0; n < LL; n++) {
        if (n < 2)       layer(n, 5,  pkg, pvg, 0);
        else if (n < 5)  layer(n, 20, pke, pve, 20 * DD);
        else             layer(n, 0,  nullptr, nullptr, 0);
    }

    // 5) final norm (row 0 of each image) + head
    ln_kernel<<<BB, 256, 0, stream>>>(xb, (long long)NN * DD, norm_s, norm_b, feat);
    head_kernel<<<(BB * NCC + 255) / 256, 256, 0, stream>>>(feat, head_w, head_b, maskf, (float*)d_out);
}